// Round 1
// baseline (3860.939 us; speedup 1.0000x reference)
//
#include <hip/hip_runtime.h>
#include <hip/hip_bf16.h>

// Problem constants
#define TCNT 8192   // B*S tokens
#define HDIM 1024
#define IDIM 2752
#define NEXP 8

typedef short bf16x8 __attribute__((ext_vector_type(8)));
typedef float floatx4 __attribute__((ext_vector_type(4)));

__device__ __forceinline__ unsigned short f2bf(float f) {
    union { float f; unsigned u; } v; v.f = f;
    unsigned u = v.u;
    unsigned r = u + 0x7FFFu + ((u >> 16) & 1u);   // RNE
    return (unsigned short)(r >> 16);
}

// ---------------- cast x fp32 -> bf16 ----------------
__global__ void cast_f32_bf16(const float* __restrict__ in,
                              unsigned short* __restrict__ out, int n) {
    int i = (blockIdx.x * blockDim.x + threadIdx.x) * 4;
    if (i + 3 < n) {
        float4 f = *(const float4*)(in + i);
        ushort4 o;
        o.x = f2bf(f.x); o.y = f2bf(f.y); o.z = f2bf(f.z); o.w = f2bf(f.w);
        *(ushort4*)(out + i) = o;
    }
}

// ---------------- gate: softmax + top2 + renorm -> dense cw[T,E] ----------------
__global__ void gate_kernel(const float* __restrict__ x,
                            const float* __restrict__ gw,
                            float* __restrict__ cw) {
    int wave = threadIdx.x >> 6;
    int lane = threadIdx.x & 63;
    int t = blockIdx.x * 4 + wave;
    float acc[NEXP];
#pragma unroll
    for (int e = 0; e < NEXP; e++) acc[e] = 0.f;
    const float* xp = x + (size_t)t * HDIM;
#pragma unroll
    for (int it = 0; it < HDIM / 64; it++) {
        float xv = xp[lane + 64 * it];
#pragma unroll
        for (int e = 0; e < NEXP; e++)
            acc[e] += xv * gw[e * HDIM + lane + 64 * it];
    }
#pragma unroll
    for (int e = 0; e < NEXP; e++) {
#pragma unroll
        for (int off = 32; off > 0; off >>= 1)
            acc[e] += __shfl_xor(acc[e], off);
    }
    if (lane == 0) {
        float m = acc[0];
#pragma unroll
        for (int e = 1; e < NEXP; e++) m = fmaxf(m, acc[e]);
        float p[NEXP], Z = 0.f;
#pragma unroll
        for (int e = 0; e < NEXP; e++) { p[e] = expf(acc[e] - m); Z += p[e]; }
        // top-2 on logits (monotonic with softmax), first-index tie-break like jax
        int i0 = 0;
#pragma unroll
        for (int e = 1; e < NEXP; e++) if (acc[e] > acc[i0]) i0 = e;
        int i1 = (i0 == 0) ? 1 : 0;
#pragma unroll
        for (int e = 0; e < NEXP; e++) {
            if (e == i0 || e == i1) continue;
            if (acc[e] > acc[i1]) i1 = e;
        }
        float p0 = p[i0] / Z, p1 = p[i1] / Z;
        float s = p0 + p1 + 1e-20f;
        float* c = cw + (size_t)t * NEXP;
#pragma unroll
        for (int e = 0; e < NEXP; e++) c[e] = 0.f;
        c[i0] = p0 / s;
        c[i1] = p1 / s;
    }
}

// ---------------- fused G/U GEMM + SwiGLU ----------------
// X[T,H] bf16 row-major; Wg,Wu [H,I] fp32 row-major (converted during staging);
// Aout[T,I] = bf16( silu(X@Wg) * (X@Wu) )
#define BM 128
#define BN 64
#define BK 32
#define LDSP 40  // padded K-row stride (ushorts); 80B, 16B-aligned chunks

__global__ __launch_bounds__(256, 2) void gemm_gu(
    const unsigned short* __restrict__ Xb,
    const float* __restrict__ Wg,
    const float* __restrict__ Wu,
    unsigned short* __restrict__ Aout) {
    __shared__ __align__(16) unsigned short Xs[BM][LDSP];  // [m][k]
    __shared__ __align__(16) unsigned short Gs[BN][LDSP];  // [n][k] (transposed)
    __shared__ __align__(16) unsigned short Us[BN][LDSP];
    const int tid = threadIdx.x;
    const int wave = tid >> 6, lane = tid & 63;
    const int quad = lane >> 4, l16 = lane & 15;
    const int m0 = blockIdx.x * BM;
    const int n0 = blockIdx.y * BN;

    floatx4 accG[2][4], accU[2][4];
#pragma unroll
    for (int mi = 0; mi < 2; mi++)
#pragma unroll
        for (int nj = 0; nj < 4; nj++) {
            accG[mi][nj] = (floatx4){0.f, 0.f, 0.f, 0.f};
            accU[mi][nj] = (floatx4){0.f, 0.f, 0.f, 0.f};
        }

    for (int kb = 0; kb < HDIM; kb += BK) {
        // stage X tile: 128 rows x 32 bf16 cols, 16B chunks
#pragma unroll
        for (int r = 0; r < 2; r++) {
            int q = tid + r * 256;          // 0..511
            int row = q >> 2, chunk = q & 3;
            *(uint4*)&Xs[row][chunk * 8] =
                *(const uint4*)(Xb + (size_t)(m0 + row) * HDIM + kb + chunk * 8);
        }
        // stage Wg/Wu tiles transposed: global [32 h][64 i] fp32 -> LDS [i][h] bf16
#pragma unroll
        for (int r = 0; r < 2; r++) {
            int q = tid + r * 256;          // 0..511 float4 chunks
            int hl = q >> 4;                // 0..31
            int il = (q & 15) * 4;          // 0..60
            float4 g = *(const float4*)(Wg + (size_t)(kb + hl) * IDIM + n0 + il);
            float4 u = *(const float4*)(Wu + (size_t)(kb + hl) * IDIM + n0 + il);
            Gs[il + 0][hl] = f2bf(g.x); Gs[il + 1][hl] = f2bf(g.y);
            Gs[il + 2][hl] = f2bf(g.z); Gs[il + 3][hl] = f2bf(g.w);
            Us[il + 0][hl] = f2bf(u.x); Us[il + 1][hl] = f2bf(u.y);
            Us[il + 2][hl] = f2bf(u.z); Us[il + 3][hl] = f2bf(u.w);
        }
        __syncthreads();

        bf16x8 af[2], bg[4], bu[4];
#pragma unroll
        for (int mi = 0; mi < 2; mi++)
            af[mi] = *(const bf16x8*)&Xs[wave * 32 + mi * 16 + l16][quad * 8];
#pragma unroll
        for (int nj = 0; nj < 4; nj++) {
            bg[nj] = *(const bf16x8*)&Gs[nj * 16 + l16][quad * 8];
            bu[nj] = *(const bf16x8*)&Us[nj * 16 + l16][quad * 8];
        }
#pragma unroll
        for (int mi = 0; mi < 2; mi++)
#pragma unroll
            for (int nj = 0; nj < 4; nj++) {
                accG[mi][nj] = __builtin_amdgcn_mfma_f32_16x16x32_bf16(
                    af[mi], bg[nj], accG[mi][nj], 0, 0, 0);
                accU[mi][nj] = __builtin_amdgcn_mfma_f32_16x16x32_bf16(
                    af[mi], bu[nj], accU[mi][nj], 0, 0, 0);
            }
        __syncthreads();
    }

    // epilogue: silu(g)*u -> bf16
#pragma unroll
    for (int mi = 0; mi < 2; mi++)
#pragma unroll
        for (int nj = 0; nj < 4; nj++)
#pragma unroll
            for (int r = 0; r < 4; r++) {
                int m = m0 + wave * 32 + mi * 16 + quad * 4 + r;
                int n = n0 + nj * 16 + l16;
                float g = accG[mi][nj][r], u = accU[mi][nj][r];
                float a = g / (1.f + expf(-g)) * u;
                Aout[(size_t)m * IDIM + n] = f2bf(a);
            }
}

// ---------------- down GEMM: Y (+)= cw[t,e] * (A @ Wd) ----------------
// A[T,I] bf16; Wd [I,H] fp32; Y[T,H] fp32
__global__ __launch_bounds__(256, 2) void gemm_down(
    const unsigned short* __restrict__ Ab,
    const float* __restrict__ Wd,
    const float* __restrict__ cw,   // null => weight 1 (shared expert)
    int eidx, int beta,
    float* __restrict__ Y) {
    __shared__ __align__(16) unsigned short As[BM][LDSP];
    __shared__ __align__(16) unsigned short Ws[BN][LDSP];
    const int tid = threadIdx.x;
    const int wave = tid >> 6, lane = tid & 63;
    const int quad = lane >> 4, l16 = lane & 15;
    const int m0 = blockIdx.x * BM;
    const int n0 = blockIdx.y * BN;

    floatx4 acc[2][4];
#pragma unroll
    for (int mi = 0; mi < 2; mi++)
#pragma unroll
        for (int nj = 0; nj < 4; nj++) acc[mi][nj] = (floatx4){0.f, 0.f, 0.f, 0.f};

    for (int kb = 0; kb < IDIM; kb += BK) {
#pragma unroll
        for (int r = 0; r < 2; r++) {
            int q = tid + r * 256;
            int row = q >> 2, chunk = q & 3;
            *(uint4*)&As[row][chunk * 8] =
                *(const uint4*)(Ab + (size_t)(m0 + row) * IDIM + kb + chunk * 8);
        }
#pragma unroll
        for (int r = 0; r < 2; r++) {
            int q = tid + r * 256;
            int hl = q >> 4;
            int il = (q & 15) * 4;
            float4 w = *(const float4*)(Wd + (size_t)(kb + hl) * HDIM + n0 + il);
            Ws[il + 0][hl] = f2bf(w.x); Ws[il + 1][hl] = f2bf(w.y);
            Ws[il + 2][hl] = f2bf(w.z); Ws[il + 3][hl] = f2bf(w.w);
        }
        __syncthreads();

        bf16x8 af[2], bf[4];
#pragma unroll
        for (int mi = 0; mi < 2; mi++)
            af[mi] = *(const bf16x8*)&As[wave * 32 + mi * 16 + l16][quad * 8];
#pragma unroll
        for (int nj = 0; nj < 4; nj++)
            bf[nj] = *(const bf16x8*)&Ws[nj * 16 + l16][quad * 8];
#pragma unroll
        for (int mi = 0; mi < 2; mi++)
#pragma unroll
            for (int nj = 0; nj < 4; nj++)
                acc[mi][nj] = __builtin_amdgcn_mfma_f32_16x16x32_bf16(
                    af[mi], bf[nj], acc[mi][nj], 0, 0, 0);
        __syncthreads();
    }

#pragma unroll
    for (int mi = 0; mi < 2; mi++)
#pragma unroll
        for (int r = 0; r < 4; r++) {
            int m = m0 + wave * 32 + mi * 16 + quad * 4 + r;
            float w = cw ? cw[(size_t)m * NEXP + eidx] : 1.0f;
#pragma unroll
            for (int nj = 0; nj < 4; nj++) {
                int n = n0 + nj * 16 + l16;
                size_t idx = (size_t)m * HDIM + n;
                float prev = beta ? Y[idx] : 0.f;
                Y[idx] = prev + w * acc[mi][nj][r];
            }
        }
}

extern "C" void kernel_launch(void* const* d_in, const int* in_sizes, int n_in,
                              void* d_out, int out_size, void* d_ws, size_t ws_size,
                              hipStream_t stream) {
    const float* x      = (const float*)d_in[0];
    const float* gate_w = (const float*)d_in[1];
    const float* wg     = (const float*)d_in[2];
    const float* wu     = (const float*)d_in[3];
    const float* wd     = (const float*)d_in[4];
    const float* sg     = (const float*)d_in[5];
    const float* su     = (const float*)d_in[6];
    const float* sd     = (const float*)d_in[7];
    float* y = (float*)d_out;

    // workspace layout
    unsigned short* Xb = (unsigned short*)d_ws;              // T*H bf16  (16.78 MB)
    unsigned short* Ab = Xb + (size_t)TCNT * HDIM;           // T*I bf16  (45.09 MB)
    float* cw = (float*)(Ab + (size_t)TCNT * IDIM);          // T*E fp32  (0.26 MB)

    // 1) cast x to bf16
    cast_f32_bf16<<<(TCNT * HDIM) / 1024, 256, 0, stream>>>(x, Xb, TCNT * HDIM);
    // 2) gate
    gate_kernel<<<TCNT / 4, 256, 0, stream>>>(x, gate_w, cw);

    dim3 g1(TCNT / BM, IDIM / BN);   // 64 x 43
    dim3 g2(TCNT / BM, HDIM / BN);   // 64 x 16
    // 3) routed experts (dense: every expert over all tokens; weights zero out unselected)
    for (int e = 0; e < NEXP; e++) {
        gemm_gu<<<g1, 256, 0, stream>>>(Xb, wg + (size_t)e * HDIM * IDIM,
                                        wu + (size_t)e * HDIM * IDIM, Ab);
        gemm_down<<<g2, 256, 0, stream>>>(Ab, wd + (size_t)e * IDIM * HDIM, cw, e,
                                          /*beta=*/e > 0 ? 1 : 0, y);
    }
    // 4) shared expert (weight 1)
    gemm_gu<<<g1, 256, 0, stream>>>(Xb, sg, su, Ab);
    gemm_down<<<g2, 256, 0, stream>>>(Ab, sd, nullptr, 0, /*beta=*/1, y);
}

// Round 2
// 1972.582 us; speedup vs baseline: 1.9573x; 1.9573x over previous
//
#include <hip/hip_runtime.h>
#include <hip/hip_bf16.h>

#define TCNT 8192   // B*S tokens
#define HDIM 1024
#define IDIM 2752
#define NEXP 8

#define BM 128
#define BN 64
#define BK 32

typedef short bf16x8 __attribute__((ext_vector_type(8)));
typedef float floatx4 __attribute__((ext_vector_type(4)));
typedef unsigned short ushort_t;

__device__ __forceinline__ unsigned short f2bf(float f) {
    union { float f; unsigned u; } v; v.f = f;
    unsigned u = v.u;
    unsigned r = u + 0x7FFFu + ((u >> 16) & 1u);   // RNE
    return (unsigned short)(r >> 16);
}

// async global->LDS, 16B per lane; LDS dest = wave-uniform base + lane*16
__device__ __forceinline__ void async16(const unsigned short* g, unsigned short* l) {
    __builtin_amdgcn_global_load_lds(
        (const __attribute__((address_space(1))) unsigned int*)g,
        (__attribute__((address_space(3))) unsigned int*)l, 16, 0, 0);
}

// ---------------- zero counters ----------------
__global__ void zero_k(int* cnt) {
    if (threadIdx.x < NEXP) cnt[threadIdx.x] = 0;
}

// ---------------- gate: softmax + top2 + compacted per-expert lists ----------------
__global__ void gate_kernel(const float* __restrict__ x,
                            const float* __restrict__ gw,
                            int* __restrict__ cnt,
                            int* __restrict__ idxb,
                            float* __restrict__ wgtb) {
    int wave = threadIdx.x >> 6;
    int lane = threadIdx.x & 63;
    int t = blockIdx.x * 4 + wave;
    float acc[NEXP];
#pragma unroll
    for (int e = 0; e < NEXP; e++) acc[e] = 0.f;
    const float* xp = x + (size_t)t * HDIM;
#pragma unroll
    for (int it = 0; it < HDIM / 64; it++) {
        float xv = xp[lane + 64 * it];
#pragma unroll
        for (int e = 0; e < NEXP; e++)
            acc[e] += xv * gw[e * HDIM + lane + 64 * it];
    }
#pragma unroll
    for (int e = 0; e < NEXP; e++) {
#pragma unroll
        for (int off = 32; off > 0; off >>= 1)
            acc[e] += __shfl_xor(acc[e], off);
    }
    if (lane == 0) {
        float m = acc[0];
#pragma unroll
        for (int e = 1; e < NEXP; e++) m = fmaxf(m, acc[e]);
        float p[NEXP], Z = 0.f;
#pragma unroll
        for (int e = 0; e < NEXP; e++) { p[e] = expf(acc[e] - m); Z += p[e]; }
        int i0 = 0;
#pragma unroll
        for (int e = 1; e < NEXP; e++) if (acc[e] > acc[i0]) i0 = e;
        int i1 = (i0 == 0) ? 1 : 0;
#pragma unroll
        for (int e = 0; e < NEXP; e++) {
            if (e == i0 || e == i1) continue;
            if (acc[e] > acc[i1]) i1 = e;
        }
        float p0 = p[i0] / Z, p1 = p[i1] / Z;
        float s = p0 + p1 + 1e-20f;
        int pos0 = atomicAdd(&cnt[i0], 1);
        idxb[i0 * TCNT + pos0] = t;
        wgtb[i0 * TCNT + pos0] = p0 / s;
        int pos1 = atomicAdd(&cnt[i1], 1);
        idxb[i1 * TCNT + pos1] = t;
        wgtb[i1 * TCNT + pos1] = p1 / s;
    }
}

// ---------------- pad lists to BM multiple (token 0, weight 0) ----------------
__global__ void pad_k(const int* __restrict__ cnt, int* __restrict__ pcnt,
                      int* __restrict__ idxb, float* __restrict__ wgtb) {
#pragma unroll
    for (int e = 0; e < NEXP; e++) {
        int c = cnt[e];
        int p = (c + BM - 1) & ~(BM - 1);
        for (int i = c + threadIdx.x; i < p; i += 256) {
            idxb[e * TCNT + i] = 0;
            wgtb[e * TCNT + i] = 0.f;
        }
        if (threadIdx.x == 0) pcnt[e] = p;
    }
}

// ---------------- transpose + cast: in fp32 [R][C] -> out bf16 [C][R] ----------------
__global__ void trans2(const float* __restrict__ in0, const float* __restrict__ in1,
                       unsigned short* __restrict__ out0, unsigned short* __restrict__ out1,
                       int R, int C) {
    const float* in = blockIdx.z ? in1 : in0;
    unsigned short* out = blockIdx.z ? out1 : out0;
    __shared__ float tile[32][33];
    int r0 = blockIdx.y * 32, c0 = blockIdx.x * 32;
    int ty = threadIdx.x >> 3, tx = (threadIdx.x & 7) * 4;
    float4 v = *(const float4*)&in[(size_t)(r0 + ty) * C + c0 + tx];
    tile[ty][tx + 0] = v.x; tile[ty][tx + 1] = v.y;
    tile[ty][tx + 2] = v.z; tile[ty][tx + 3] = v.w;
    __syncthreads();
    int cy = ty, rx = tx;
    ushort4 o;
    o.x = f2bf(tile[rx + 0][cy]); o.y = f2bf(tile[rx + 1][cy]);
    o.z = f2bf(tile[rx + 2][cy]); o.w = f2bf(tile[rx + 3][cy]);
    *(ushort4*)&out[(size_t)(c0 + cy) * R + r0 + rx] = o;
}

// ---------------- fused G/U GEMM + SwiGLU (gathered rows) ----------------
// x [T,H] fp32; GT,UT [I,H] bf16 (pre-transposed); Aout [cap,I] bf16
__global__ void gemm_gu(const float* __restrict__ x,
                        const unsigned short* __restrict__ GT,
                        const unsigned short* __restrict__ UT,
                        const int* __restrict__ idx,    // per-expert list (+e*T) or null
                        const int* __restrict__ pcnt,   // padded count ptr or null
                        unsigned short* __restrict__ Aout) {
    const int m0 = blockIdx.x * BM;
    const int cnt = pcnt ? *pcnt : TCNT;
    if (m0 >= cnt) return;
    const int n0 = blockIdx.y * BN;

    __shared__ unsigned short Xs[BM][BK];   // unpadded (async-copy layout)
    __shared__ unsigned short Gs[BN][BK];
    __shared__ unsigned short Us[BN][BK];
    __shared__ int toks[BM];

    const int tid = threadIdx.x;
    const int wave = tid >> 6, lane = tid & 63;
    const int quad = lane >> 4, l16 = lane & 15;
    const int wm = wave >> 1, wn = wave & 1;   // wave tile: 64 m x 32 n

    if (tid < BM) toks[tid] = idx ? idx[m0 + tid] : (m0 + tid);
    __syncthreads();

    floatx4 aG[4][2], aU[4][2];
#pragma unroll
    for (int mi = 0; mi < 4; mi++)
#pragma unroll
        for (int nj = 0; nj < 2; nj++) {
            aG[mi][nj] = (floatx4){0.f, 0.f, 0.f, 0.f};
            aU[mi][nj] = (floatx4){0.f, 0.f, 0.f, 0.f};
        }

    const int rr = lane >> 2, cc = lane & 3;
    for (int kb = 0; kb < HDIM; kb += BK) {
        // weights: async 16B/lane, one wave stages 16 rows per matrix
        async16(GT + (size_t)(n0 + wave * 16 + rr) * HDIM + kb + cc * 8, &Gs[wave * 16][0]);
        async16(UT + (size_t)(n0 + wave * 16 + rr) * HDIM + kb + cc * 8, &Us[wave * 16][0]);
        // X: gather rows, convert fp32->bf16 in-register, vector 8B stores
#pragma unroll
        for (int r = 0; r < 4; r++) {
            int q = tid + r * 256;          // 0..1023
            int row = q >> 3, c = q & 7;
            const float* src = x + (size_t)toks[row] * HDIM + kb + c * 4;
            float4 v = *(const float4*)src;
            ushort4 o;
            o.x = f2bf(v.x); o.y = f2bf(v.y); o.z = f2bf(v.z); o.w = f2bf(v.w);
            *(ushort4*)&Xs[row][c * 4] = o;
        }
        __syncthreads();

        bf16x8 af[4], bg[2], bu[2];
#pragma unroll
        for (int mi = 0; mi < 4; mi++)
            af[mi] = *(const bf16x8*)&Xs[wm * 64 + mi * 16 + l16][quad * 8];
#pragma unroll
        for (int nj = 0; nj < 2; nj++) {
            bg[nj] = *(const bf16x8*)&Gs[wn * 32 + nj * 16 + l16][quad * 8];
            bu[nj] = *(const bf16x8*)&Us[wn * 32 + nj * 16 + l16][quad * 8];
        }
#pragma unroll
        for (int mi = 0; mi < 4; mi++)
#pragma unroll
            for (int nj = 0; nj < 2; nj++) {
                aG[mi][nj] = __builtin_amdgcn_mfma_f32_16x16x32_bf16(af[mi], bg[nj], aG[mi][nj], 0, 0, 0);
                aU[mi][nj] = __builtin_amdgcn_mfma_f32_16x16x32_bf16(af[mi], bu[nj], aU[mi][nj], 0, 0, 0);
            }
        __syncthreads();
    }

#pragma unroll
    for (int mi = 0; mi < 4; mi++)
#pragma unroll
        for (int nj = 0; nj < 2; nj++)
#pragma unroll
            for (int r = 0; r < 4; r++) {
                int m = m0 + wm * 64 + mi * 16 + quad * 4 + r;
                int n = n0 + wn * 32 + nj * 16 + l16;
                float g = aG[mi][nj][r], u = aU[mi][nj][r];
                float a = g / (1.f + expf(-g)) * u;
                Aout[(size_t)m * IDIM + n] = f2bf(a);
            }
}

// ---------------- down GEMM: scatter-add w * (A @ WdT^T) into Y ----------------
// Ab [cap,I] bf16; WdT [H,I] bf16 (pre-transposed); Y [T,H] fp32
__global__ void gemm_down(const unsigned short* __restrict__ Ab,
                          const unsigned short* __restrict__ WdT,
                          const int* __restrict__ idx,
                          const float* __restrict__ wgt,
                          const int* __restrict__ pcnt,
                          float* __restrict__ Y) {
    const int m0 = blockIdx.x * BM;
    const int cnt = pcnt ? *pcnt : TCNT;
    if (m0 >= cnt) return;
    const int n0 = blockIdx.y * BN;

    __shared__ unsigned short As[BM][BK];
    __shared__ unsigned short Ws[BN][BK];
    __shared__ int toks[BM];
    __shared__ float tw[BM];

    const int tid = threadIdx.x;
    const int wave = tid >> 6, lane = tid & 63;
    const int quad = lane >> 4, l16 = lane & 15;
    const int wm = wave >> 1, wn = wave & 1;

    if (tid < BM) {
        toks[tid] = idx ? idx[m0 + tid] : (m0 + tid);
        tw[tid] = wgt ? wgt[m0 + tid] : 1.0f;
    }
    __syncthreads();

    floatx4 acc[4][2];
#pragma unroll
    for (int mi = 0; mi < 4; mi++)
#pragma unroll
        for (int nj = 0; nj < 2; nj++) acc[mi][nj] = (floatx4){0.f, 0.f, 0.f, 0.f};

    const int rr = lane >> 2, cc = lane & 3;
    for (int kb = 0; kb < IDIM; kb += BK) {
#pragma unroll
        for (int s = 0; s < 2; s++) {
            int seg = wave * 2 + s;   // 0..7, 16 rows each
            async16(Ab + (size_t)(m0 + seg * 16 + rr) * IDIM + kb + cc * 8, &As[seg * 16][0]);
        }
        async16(WdT + (size_t)(n0 + wave * 16 + rr) * IDIM + kb + cc * 8, &Ws[wave * 16][0]);
        __syncthreads();

        bf16x8 af[4], bw[2];
#pragma unroll
        for (int mi = 0; mi < 4; mi++)
            af[mi] = *(const bf16x8*)&As[wm * 64 + mi * 16 + l16][quad * 8];
#pragma unroll
        for (int nj = 0; nj < 2; nj++)
            bw[nj] = *(const bf16x8*)&Ws[wn * 32 + nj * 16 + l16][quad * 8];
#pragma unroll
        for (int mi = 0; mi < 4; mi++)
#pragma unroll
            for (int nj = 0; nj < 2; nj++)
                acc[mi][nj] = __builtin_amdgcn_mfma_f32_16x16x32_bf16(af[mi], bw[nj], acc[mi][nj], 0, 0, 0);
        __syncthreads();
    }

    if (idx) {  // routed: scatter atomic add (pad rows have weight 0)
#pragma unroll
        for (int mi = 0; mi < 4; mi++)
#pragma unroll
            for (int r = 0; r < 4; r++) {
                int lm = wm * 64 + mi * 16 + quad * 4 + r;
                int t = toks[lm];
                float w = tw[lm];
#pragma unroll
                for (int nj = 0; nj < 2; nj++) {
                    int n = n0 + wn * 32 + nj * 16 + l16;
                    atomicAdd(&Y[(size_t)t * HDIM + n], w * acc[mi][nj][r]);
                }
            }
    } else {    // shared expert: direct store (runs first, initializes Y)
#pragma unroll
        for (int mi = 0; mi < 4; mi++)
#pragma unroll
            for (int r = 0; r < 4; r++) {
                int m = m0 + wm * 64 + mi * 16 + quad * 4 + r;
#pragma unroll
                for (int nj = 0; nj < 2; nj++) {
                    int n = n0 + wn * 32 + nj * 16 + l16;
                    Y[(size_t)m * HDIM + n] = acc[mi][nj][r];
                }
            }
    }
}

extern "C" void kernel_launch(void* const* d_in, const int* in_sizes, int n_in,
                              void* d_out, int out_size, void* d_ws, size_t ws_size,
                              hipStream_t stream) {
    const float* x      = (const float*)d_in[0];
    const float* gate_w = (const float*)d_in[1];
    const float* wg     = (const float*)d_in[2];
    const float* wu     = (const float*)d_in[3];
    const float* wd     = (const float*)d_in[4];
    const float* sg     = (const float*)d_in[5];
    const float* su     = (const float*)d_in[6];
    const float* sd     = (const float*)d_in[7];
    float* y = (float*)d_out;

    const size_t HI = (size_t)HDIM * IDIM;
    unsigned short* WgT = (unsigned short*)d_ws;            // [I,H] bf16
    unsigned short* WuT = WgT + HI;                          // [I,H] bf16
    unsigned short* Ab  = WuT + HI;                          // [T,I] bf16
    int*   idxb = (int*)(Ab + (size_t)TCNT * IDIM);          // [E,T]
    float* wgtb = (float*)(idxb + NEXP * TCNT);              // [E,T]
    int*   cnt  = (int*)(wgtb + NEXP * TCNT);                // [E]
    int*   pcnt = cnt + NEXP;                                // [E]
    unsigned short* WdT = WgT;  // alias: WgT dead once gemm_gu(e) done; serialized on stream

    zero_k<<<1, 64, 0, stream>>>(cnt);
    gate_kernel<<<TCNT / 4, 256, 0, stream>>>(x, gate_w, cnt, idxb, wgtb);
    pad_k<<<1, 256, 0, stream>>>(cnt, pcnt, idxb, wgtb);

    dim3 tg(IDIM / 32, HDIM / 32, 2);   // [H,I] -> [I,H], g+u
    dim3 td(HDIM / 32, IDIM / 32, 1);   // [I,H] -> [H,I]
    dim3 g1(TCNT / BM, IDIM / BN);      // 64 x 43
    dim3 g2(TCNT / BM, HDIM / BN);      // 64 x 16

    // shared expert first: down writes Y directly (no atomics)
    trans2<<<tg, 256, 0, stream>>>(sg, su, WgT, WuT, HDIM, IDIM);
    gemm_gu<<<g1, 256, 0, stream>>>(x, WgT, WuT, nullptr, nullptr, Ab);
    trans2<<<td, 256, 0, stream>>>(sd, sd, WdT, WdT, IDIM, HDIM);
    gemm_down<<<g2, 256, 0, stream>>>(Ab, WdT, nullptr, nullptr, nullptr, y);

    // routed experts: compacted token lists, scatter-add
    for (int e = 0; e < NEXP; e++) {
        trans2<<<tg, 256, 0, stream>>>(wg + (size_t)e * HI, wu + (size_t)e * HI,
                                       WgT, WuT, HDIM, IDIM);
        gemm_gu<<<g1, 256, 0, stream>>>(x, WgT, WuT, idxb + e * TCNT, pcnt + e, Ab);
        trans2<<<td, 256, 0, stream>>>(wd + (size_t)e * HI, wd, WdT, WdT, IDIM, HDIM);
        gemm_down<<<g2, 256, 0, stream>>>(Ab, WdT, idxb + e * TCNT, wgtb + e * TCNT,
                                          pcnt + e, y);
    }
}